// Round 1
// baseline (570.498 us; speedup 1.0000x reference)
//
#include <hip/hip_runtime.h>
#include <hip/hip_bf16.h>

#define B_ 4
#define T_ 2048
#define D_ 1024
#define H_ 16
#define HD_ 64

typedef __bf16 bf16;
typedef __bf16 bf16x8 __attribute__((ext_vector_type(8)));
typedef __bf16 bf16x4 __attribute__((ext_vector_type(4)));
typedef float f32x4 __attribute__((ext_vector_type(4)));

#define MFMA16(a, b, c) __builtin_amdgcn_mfma_f32_16x16x32_bf16(a, b, c, 0, 0, 0)

__device__ inline void gld_lds16(const bf16* g, bf16* l) {
  __builtin_amdgcn_global_load_lds((const __attribute__((address_space(1))) void*)g,
                                   (__attribute__((address_space(3))) void*)l, 16, 0, 0);
}

// ---------------- convert x f32 -> bf16 ----------------
__global__ void cvt_f32_bf16(const float* __restrict__ in, bf16* __restrict__ out) {
  int i = (blockIdx.x * 256 + threadIdx.x) * 4;
  float4 v = *(const float4*)(in + i);
  bf16x4 o = {(bf16)v.x, (bf16)v.y, (bf16)v.z, (bf16)v.w};
  *(bf16x4*)(out + i) = o;
}

// ---------------- transpose f32 [R][C] -> bf16 [C][R] ----------------
__global__ void transpose_f32_bf16(const float* __restrict__ in, bf16* __restrict__ out,
                                   int R, int C) {
  __shared__ float tile[32][33];
  int c0 = blockIdx.x * 32, r0 = blockIdx.y * 32;
  int tx = threadIdx.x, ty = threadIdx.y;
#pragma unroll
  for (int i = 0; i < 4; i++)
    tile[ty + i * 8][tx] = in[(size_t)(r0 + ty + i * 8) * C + c0 + tx];
  __syncthreads();
#pragma unroll
  for (int i = 0; i < 4; i++)
    out[(size_t)(c0 + ty + i * 8) * R + r0 + tx] = (bf16)tile[tx][ty + i * 8];
}

// ---------------- transpose V bf16 [bh][T][64] -> [bh][64][T] ----------------
__global__ void transpose_v(const bf16* __restrict__ in, bf16* __restrict__ out) {
  __shared__ bf16 tile[32][33];
  int bh = blockIdx.y;
  int t0 = blockIdx.x * 32;
  int tx = threadIdx.x, ty = threadIdx.y;
  const bf16* ib = in + (size_t)bh * T_ * HD_;
  bf16* ob = out + (size_t)bh * HD_ * T_;
#pragma unroll
  for (int d0 = 0; d0 < 64; d0 += 32) {
#pragma unroll
    for (int i = 0; i < 4; i++)
      tile[ty + i * 8][tx] = ib[(size_t)(t0 + ty + i * 8) * HD_ + d0 + tx];
    __syncthreads();
#pragma unroll
    for (int i = 0; i < 4; i++)
      ob[(size_t)(d0 + ty + i * 8) * T_ + t0 + tx] = tile[tx][ty + i * 8];
    __syncthreads();
  }
}

// ---------------- 128x128 bf16 GEMM, B transposed ([N][K]) ----------------
// EPI 0: qkv scatter epilogue. EPI 1: plain f32 store.
template <int EPI>
__global__ __launch_bounds__(256) void gemm_bt(const bf16* __restrict__ A,
                                               const bf16* __restrict__ Bt,
                                               bf16* __restrict__ qb, bf16* __restrict__ kb,
                                               bf16* __restrict__ vb, float* __restrict__ fout,
                                               int M, int N, int K) {
  __shared__ __align__(16) bf16 lds_a[128 * 32];
  __shared__ __align__(16) bf16 lds_b[128 * 32];
  int n0 = blockIdx.x * 128, m0 = blockIdx.y * 128;
  int tid = threadIdx.x, wave = tid >> 6, lane = tid & 63;
  int l16 = lane & 15, lhi = lane >> 4;
  int wr = wave >> 1, wc = wave & 1;
  f32x4 acc[4][4];
#pragma unroll
  for (int mt = 0; mt < 4; mt++)
#pragma unroll
    for (int nt = 0; nt < 4; nt++) acc[mt][nt] = (f32x4){0.f, 0.f, 0.f, 0.f};

  int sr = wave * 16 + (lane >> 2);   // staging row 0..63
  int scol = (lane & 3) * 8;          // staging col (elements)
  const bf16* ga = A + (size_t)(m0 + sr) * K + scol;
  const bf16* gb = Bt + (size_t)(n0 + sr) * K + scol;
  bf16* la0 = &lds_a[wave * 512];
  bf16* la1 = &lds_a[2048 + wave * 512];
  bf16* lb0 = &lds_b[wave * 512];
  bf16* lb1 = &lds_b[2048 + wave * 512];

  for (int k0 = 0; k0 < K; k0 += 32) {
    gld_lds16(ga + k0, la0);
    gld_lds16(ga + (size_t)64 * K + k0, la1);
    gld_lds16(gb + k0, lb0);
    gld_lds16(gb + (size_t)64 * K + k0, lb1);
    __syncthreads();
    bf16x8 af[4], bfr[4];
#pragma unroll
    for (int mt = 0; mt < 4; mt++)
      af[mt] = *(const bf16x8*)&lds_a[(wr * 64 + mt * 16 + l16) * 32 + 8 * lhi];
#pragma unroll
    for (int nt = 0; nt < 4; nt++)
      bfr[nt] = *(const bf16x8*)&lds_b[(wc * 64 + nt * 16 + l16) * 32 + 8 * lhi];
#pragma unroll
    for (int mt = 0; mt < 4; mt++)
#pragma unroll
      for (int nt = 0; nt < 4; nt++) acc[mt][nt] = MFMA16(af[mt], bfr[nt], acc[mt][nt]);
    __syncthreads();
  }

#pragma unroll
  for (int mt = 0; mt < 4; mt++)
#pragma unroll
    for (int nt = 0; nt < 4; nt++)
#pragma unroll
      for (int rr = 0; rr < 4; rr++) {
        int row = m0 + wr * 64 + mt * 16 + 4 * lhi + rr;
        int col = n0 + wc * 64 + nt * 16 + l16;
        float v = acc[mt][nt][rr];
        if (EPI == 0) {
          int b = row >> 11, t = row & (T_ - 1);
          int sec = col >> 10, c2 = col & 1023;
          int h = c2 >> 6, d = c2 & 63;
          size_t idx = ((size_t)(b * H_ + h) * T_ + t) * HD_ + d;
          if (sec == 0)
            qb[idx] = (bf16)(v * 0.03125f);  // SCALE = D^-0.5 = 1/32 folded into Q
          else if (sec == 1)
            kb[idx] = (bf16)v;
          else
            vb[idx] = (bf16)v;
        } else {
          fout[(size_t)row * N + col] = v;
        }
      }
}

// ---------------- causal flash attention ----------------
// grid (T/64, B*H), 256 thr. Each wave owns 16 q rows, independent.
__global__ __launch_bounds__(256) void attn_kernel(const bf16* __restrict__ qbuf,
                                                   const bf16* __restrict__ kbuf,
                                                   const bf16* __restrict__ vtbuf,
                                                   bf16* __restrict__ obuf) {
  __shared__ __align__(16) bf16 plds[4][16 * 64];
  int bh = blockIdx.y;
  int wave = threadIdx.x >> 6, lane = threadIdx.x & 63;
  int l16 = lane & 15, lhi = lane >> 4;
  int qr0 = blockIdx.x * 64 + wave * 16;
  const bf16* Q = qbuf + (size_t)bh * T_ * HD_;
  const bf16* K = kbuf + (size_t)bh * T_ * HD_;
  const bf16* Vt = vtbuf + (size_t)bh * HD_ * T_;

  bf16x8 qf0 = *(const bf16x8*)(Q + (size_t)(qr0 + l16) * HD_ + 8 * lhi);
  bf16x8 qf1 = *(const bf16x8*)(Q + (size_t)(qr0 + l16) * HD_ + 32 + 8 * lhi);

  f32x4 acc[4];
#pragma unroll
  for (int dt = 0; dt < 4; dt++) acc[dt] = (f32x4){0.f, 0.f, 0.f, 0.f};
  float m_r[4], l_r[4];
#pragma unroll
  for (int rr = 0; rr < 4; rr++) {
    m_r[rr] = -1e30f;
    l_r[rr] = 0.f;
  }
  bf16* pb = plds[wave];
  int ntile = (qr0 + 15) / 64 + 1;

  for (int t = 0; t < ntile; ++t) {
    int jb = t * 64;
    f32x4 s[4];
#pragma unroll
    for (int jt = 0; jt < 4; jt++) {
      const bf16* kp = K + (size_t)(jb + jt * 16 + l16) * HD_ + 8 * lhi;
      bf16x8 kf0 = *(const bf16x8*)kp;
      bf16x8 kf1 = *(const bf16x8*)(kp + 32);
      f32x4 z = (f32x4){0.f, 0.f, 0.f, 0.f};
      z = MFMA16(qf0, kf0, z);
      s[jt] = MFMA16(qf1, kf1, z);
    }
    if (jb + 63 > qr0) {
#pragma unroll
      for (int jt = 0; jt < 4; jt++)
#pragma unroll
        for (int rr = 0; rr < 4; rr++)
          if (jb + jt * 16 + l16 > qr0 + 4 * lhi + rr) s[jt][rr] = -1e30f;
    }
    // row-wise softmax (rows live across the 16-lane group)
    float mx[4], sum[4], sc[4];
#pragma unroll
    for (int rr = 0; rr < 4; rr++)
      mx[rr] = fmaxf(fmaxf(s[0][rr], s[1][rr]), fmaxf(s[2][rr], s[3][rr]));
#pragma unroll
    for (int off = 1; off < 16; off <<= 1)
#pragma unroll
      for (int rr = 0; rr < 4; rr++) mx[rr] = fmaxf(mx[rr], __shfl_xor(mx[rr], off));
    float p[4][4];
#pragma unroll
    for (int rr = 0; rr < 4; rr++) {
      float mn = fmaxf(m_r[rr], mx[rr]);
      sc[rr] = __expf(m_r[rr] - mn);
      m_r[rr] = mn;
      float su = 0.f;
#pragma unroll
      for (int jt = 0; jt < 4; jt++) {
        p[jt][rr] = __expf(s[jt][rr] - mn);
        su += p[jt][rr];
      }
      sum[rr] = su;
    }
#pragma unroll
    for (int off = 1; off < 16; off <<= 1)
#pragma unroll
      for (int rr = 0; rr < 4; rr++) sum[rr] += __shfl_xor(sum[rr], off);
#pragma unroll
    for (int rr = 0; rr < 4; rr++) l_r[rr] = l_r[rr] * sc[rr] + sum[rr];
#pragma unroll
    for (int dt = 0; dt < 4; dt++)
#pragma unroll
      for (int rr = 0; rr < 4; rr++) acc[dt][rr] *= sc[rr];

    // stage P (bf16) into per-wave LDS with XOR swizzle
#pragma unroll
    for (int jt = 0; jt < 4; jt++)
#pragma unroll
      for (int rr = 0; rr < 4; rr++) {
        int row = 4 * lhi + rr;
        int byte = (row * 128 + (jt * 16 + l16) * 2) ^ ((row & 7) << 4);
        *(bf16*)((char*)pb + byte) = (bf16)p[jt][rr];
      }
    bf16x8 pf[2];
#pragma unroll
    for (int kk = 0; kk < 2; kk++) {
      int byte = (l16 * 128 + kk * 64 + lhi * 16) ^ ((l16 & 7) << 4);
      pf[kk] = *(const bf16x8*)((char*)pb + byte);
    }
#pragma unroll
    for (int dt = 0; dt < 4; dt++) {
      const bf16* vp = Vt + (size_t)(dt * 16 + l16) * T_ + jb + 8 * lhi;
      bf16x8 vf0 = *(const bf16x8*)vp;
      bf16x8 vf1 = *(const bf16x8*)(vp + 32);
      acc[dt] = MFMA16(pf[0], vf0, acc[dt]);
      acc[dt] = MFMA16(pf[1], vf1, acc[dt]);
    }
  }

  int b = bh >> 4, h = bh & 15;
#pragma unroll
  for (int dt = 0; dt < 4; dt++)
#pragma unroll
    for (int rr = 0; rr < 4; rr++) {
      int row = qr0 + 4 * lhi + rr;
      obuf[((size_t)(b * T_ + row)) * D_ + h * 64 + dt * 16 + l16] =
          (bf16)(acc[dt][rr] / l_r[rr]);
    }
}

extern "C" void kernel_launch(void* const* d_in, const int* in_sizes, int n_in, void* d_out,
                              int out_size, void* d_ws, size_t ws_size, hipStream_t stream) {
  const float* x = (const float*)d_in[0];
  const float* wqkv = (const float*)d_in[1];
  const float* wo = (const float*)d_in[2];
  float* out = (float*)d_out;
  char* ws = (char*)d_ws;

  bf16* xb = (bf16*)ws;                       // 16 MB  [8192][1024]
  bf16* wqkvt = (bf16*)(ws + (16u << 20));    // 6 MB   [3072][1024]
  bf16* wot = (bf16*)(ws + (22u << 20));      // 2 MB   [1024][1024]
  bf16* qb = (bf16*)(ws + (24u << 20));       // 16 MB  [B,H,T,64]
  bf16* kb = (bf16*)(ws + (40u << 20));       // 16 MB  [B,H,T,64]
  bf16* vb = (bf16*)(ws + (56u << 20));       // 16 MB  [B,H,T,64]
  bf16* vtb = (bf16*)(ws + (72u << 20));      // 16 MB  [B,H,64,T]
  bf16* ao = (bf16*)(ws + (88u << 20));       // 16 MB  [8192][1024]

  cvt_f32_bf16<<<8192, 256, 0, stream>>>(x, xb);
  transpose_f32_bf16<<<dim3(96, 32), dim3(32, 8), 0, stream>>>(wqkv, wqkvt, 1024, 3072);
  transpose_f32_bf16<<<dim3(32, 32), dim3(32, 8), 0, stream>>>(wo, wot, 1024, 1024);
  gemm_bt<0><<<dim3(24, 64), 256, 0, stream>>>(xb, wqkvt, qb, kb, vb, nullptr,
                                               B_ * T_, 3 * D_, D_);
  transpose_v<<<dim3(64, 64), dim3(32, 8), 0, stream>>>(vb, vtb);
  attn_kernel<<<dim3(32, 64), 256, 0, stream>>>(qb, kb, vtb, ao);
  gemm_bt<1><<<dim3(8, 64), 256, 0, stream>>>(ao, wot, nullptr, nullptr, nullptr, out,
                                              B_ * T_, D_, D_);
}

// Round 2
// 306.085 us; speedup vs baseline: 1.8639x; 1.8639x over previous
//
#include <hip/hip_runtime.h>
#include <hip/hip_bf16.h>

#define B_ 4
#define T_ 2048
#define D_ 1024
#define H_ 16
#define HD_ 64

typedef __bf16 bf16;
typedef __bf16 bf16x8 __attribute__((ext_vector_type(8)));
typedef __bf16 bf16x4 __attribute__((ext_vector_type(4)));
typedef float f32x4 __attribute__((ext_vector_type(4)));

#define MFMA16(a, b, c) __builtin_amdgcn_mfma_f32_16x16x32_bf16(a, b, c, 0, 0, 0)

__device__ inline void gld_lds16(const bf16* g, bf16* l) {
  __builtin_amdgcn_global_load_lds((const __attribute__((address_space(1))) void*)g,
                                   (__attribute__((address_space(3))) void*)l, 16, 0, 0);
}

// ---------------- convert x f32 -> bf16 ----------------
__global__ void cvt_f32_bf16(const float* __restrict__ in, bf16* __restrict__ out) {
  int i = (blockIdx.x * 256 + threadIdx.x) * 4;
  float4 v = *(const float4*)(in + i);
  bf16x4 o = {(bf16)v.x, (bf16)v.y, (bf16)v.z, (bf16)v.w};
  *(bf16x4*)(out + i) = o;
}

// ---------------- transpose f32 [R][C] -> bf16 [C][R] ----------------
__global__ void transpose_f32_bf16(const float* __restrict__ in, bf16* __restrict__ out,
                                   int R, int C) {
  __shared__ float tile[32][33];
  int c0 = blockIdx.x * 32, r0 = blockIdx.y * 32;
  int tx = threadIdx.x, ty = threadIdx.y;
#pragma unroll
  for (int i = 0; i < 4; i++)
    tile[ty + i * 8][tx] = in[(size_t)(r0 + ty + i * 8) * C + c0 + tx];
  __syncthreads();
#pragma unroll
  for (int i = 0; i < 4; i++)
    out[(size_t)(c0 + ty + i * 8) * R + r0 + tx] = (bf16)tile[tx][ty + i * 8];
}

// ---------------- transpose V bf16 [bh][T][64] -> [bh][64][T] ----------------
__global__ void transpose_v(const bf16* __restrict__ in, bf16* __restrict__ out) {
  __shared__ bf16 tile[32][33];
  int bh = blockIdx.y;
  int t0 = blockIdx.x * 32;
  int tx = threadIdx.x, ty = threadIdx.y;
  const bf16* ib = in + (size_t)bh * T_ * HD_;
  bf16* ob = out + (size_t)bh * HD_ * T_;
#pragma unroll
  for (int d0 = 0; d0 < 64; d0 += 32) {
#pragma unroll
    for (int i = 0; i < 4; i++)
      tile[ty + i * 8][tx] = ib[(size_t)(t0 + ty + i * 8) * HD_ + d0 + tx];
    __syncthreads();
#pragma unroll
    for (int i = 0; i < 4; i++)
      ob[(size_t)(d0 + ty + i * 8) * T_ + t0 + tx] = tile[tx][ty + i * 8];
    __syncthreads();
  }
}

// ---------------- 128x128 bf16 GEMM, B transposed ([N][K]) ----------------
template <int EPI>
__global__ __launch_bounds__(256) void gemm_bt(const bf16* __restrict__ A,
                                               const bf16* __restrict__ Bt,
                                               bf16* __restrict__ qb, bf16* __restrict__ kb,
                                               bf16* __restrict__ vb, float* __restrict__ fout,
                                               int M, int N, int K) {
  __shared__ __align__(16) bf16 lds_a[128 * 32];
  __shared__ __align__(16) bf16 lds_b[128 * 32];
  int n0 = blockIdx.x * 128, m0 = blockIdx.y * 128;
  int tid = threadIdx.x, wave = tid >> 6, lane = tid & 63;
  int l16 = lane & 15, lhi = lane >> 4;
  int wr = wave >> 1, wc = wave & 1;
  f32x4 acc[4][4];
#pragma unroll
  for (int mt = 0; mt < 4; mt++)
#pragma unroll
    for (int nt = 0; nt < 4; nt++) acc[mt][nt] = (f32x4){0.f, 0.f, 0.f, 0.f};

  int sr = wave * 16 + (lane >> 2);
  int scol = (lane & 3) * 8;
  const bf16* ga = A + (size_t)(m0 + sr) * K + scol;
  const bf16* gb = Bt + (size_t)(n0 + sr) * K + scol;
  bf16* la0 = &lds_a[wave * 512];
  bf16* la1 = &lds_a[2048 + wave * 512];
  bf16* lb0 = &lds_b[wave * 512];
  bf16* lb1 = &lds_b[2048 + wave * 512];

  for (int k0 = 0; k0 < K; k0 += 32) {
    gld_lds16(ga + k0, la0);
    gld_lds16(ga + (size_t)64 * K + k0, la1);
    gld_lds16(gb + k0, lb0);
    gld_lds16(gb + (size_t)64 * K + k0, lb1);
    __syncthreads();
    bf16x8 af[4], bfr[4];
#pragma unroll
    for (int mt = 0; mt < 4; mt++)
      af[mt] = *(const bf16x8*)&lds_a[(wr * 64 + mt * 16 + l16) * 32 + 8 * lhi];
#pragma unroll
    for (int nt = 0; nt < 4; nt++)
      bfr[nt] = *(const bf16x8*)&lds_b[(wc * 64 + nt * 16 + l16) * 32 + 8 * lhi];
#pragma unroll
    for (int mt = 0; mt < 4; mt++)
#pragma unroll
      for (int nt = 0; nt < 4; nt++) acc[mt][nt] = MFMA16(af[mt], bfr[nt], acc[mt][nt]);
    __syncthreads();
  }

#pragma unroll
  for (int mt = 0; mt < 4; mt++)
#pragma unroll
    for (int nt = 0; nt < 4; nt++)
#pragma unroll
      for (int rr = 0; rr < 4; rr++) {
        int row = m0 + wr * 64 + mt * 16 + 4 * lhi + rr;
        int col = n0 + wc * 64 + nt * 16 + l16;
        float v = acc[mt][nt][rr];
        if (EPI == 0) {
          int b = row >> 11, t = row & (T_ - 1);
          int sec = col >> 10, c2 = col & 1023;
          int h = c2 >> 6, d = c2 & 63;
          size_t idx = ((size_t)(b * H_ + h) * T_ + t) * HD_ + d;
          if (sec == 0)
            qb[idx] = (bf16)(v * 0.03125f);  // SCALE = D^-0.5 = 1/32 folded into Q
          else if (sec == 1)
            kb[idx] = (bf16)v;
          else
            vb[idx] = (bf16)v;
        } else {
          fout[(size_t)row * N + col] = v;
        }
      }
}

// ---------------- causal flash attention v2 ----------------
// 1D grid of 1024 blocks (XCD-swizzled), 256 thr. Block owns 128 q rows
// (32/wave); K and V^T tiles (64x64) double-buffered in LDS, XOR-swizzled
// via pre-swizzled global source (linear gld_lds dest).
__global__ __launch_bounds__(256) void attn_kernel(const bf16* __restrict__ qbuf,
                                                   const bf16* __restrict__ kbuf,
                                                   const bf16* __restrict__ vtbuf,
                                                   bf16* __restrict__ obuf) {
  __shared__ __align__(16) bf16 kt[2][64 * 64];
  __shared__ __align__(16) bf16 vt[2][64 * 64];
  __shared__ __align__(16) bf16 plds[4][32 * 64];

  int bid = blockIdx.x;
  int swz = (bid & 7) * 128 + (bid >> 3);  // XCD k owns bh [8k, 8k+8)
  int bh = swz >> 4;
  int bx = 15 - (swz & 15);  // heavy diagonal blocks first
  int q0 = bx * 128;
  int wave = threadIdx.x >> 6, lane = threadIdx.x & 63;
  int l16 = lane & 15, lhi = lane >> 4;
  int qw = q0 + wave * 32;

  const bf16* Q = qbuf + (size_t)bh * T_ * HD_;
  const bf16* Kg = kbuf + (size_t)bh * T_ * HD_;
  const bf16* Vt = vtbuf + (size_t)bh * HD_ * T_;

  bf16x8 qf[2][2];
#pragma unroll
  for (int i = 0; i < 2; i++)
#pragma unroll
    for (int kk = 0; kk < 2; kk++)
      qf[i][kk] = *(const bf16x8*)(Q + (size_t)(qw + i * 16 + l16) * HD_ + kk * 32 + 8 * lhi);

  f32x4 acc[2][4];
#pragma unroll
  for (int i = 0; i < 2; i++)
#pragma unroll
    for (int dt = 0; dt < 4; dt++) acc[i][dt] = (f32x4){0.f, 0.f, 0.f, 0.f};
  float m_r[2][4], l_r[2][4];
#pragma unroll
  for (int i = 0; i < 2; i++)
#pragma unroll
    for (int rr = 0; rr < 4; rr++) {
      m_r[i][rr] = -1e30f;
      l_r[i][rr] = 0.f;
    }

  // staging geometry: wave stages rows [16w,16w+16) of each 64x64 tile;
  // source col pre-swizzled so linear LDS + swizzled read = XOR-swizzle.
  int srow = lane >> 3;                       // 0..7
  int sc8 = ((lane & 7) ^ srow) * 8;          // pre-swizzled col (elems)
  int r0 = wave * 16;

  int nt = 2 * bx + 2;  // block-uniform tile count

  // prologue: stage tile 0 into buf 0
  {
    gld_lds16(Kg + (size_t)(r0 + srow) * HD_ + sc8, &kt[0][r0 * 64]);
    gld_lds16(Kg + (size_t)(r0 + 8 + srow) * HD_ + sc8, &kt[0][(r0 + 8) * 64]);
    gld_lds16(Vt + (size_t)(r0 + srow) * T_ + sc8, &vt[0][r0 * 64]);
    gld_lds16(Vt + (size_t)(r0 + 8 + srow) * T_ + sc8, &vt[0][(r0 + 8) * 64]);
  }
  __syncthreads();

  bf16* pb = plds[wave];

  for (int t = 0; t < nt; ++t) {
    int jb = t * 64;
    int cur = t & 1;
    if (t + 1 < nt) {
      int jn = jb + 64;
      int nb = cur ^ 1;
      gld_lds16(Kg + (size_t)(jn + r0 + srow) * HD_ + sc8, &kt[nb][r0 * 64]);
      gld_lds16(Kg + (size_t)(jn + r0 + 8 + srow) * HD_ + sc8, &kt[nb][(r0 + 8) * 64]);
      gld_lds16(Vt + (size_t)(r0 + srow) * T_ + jn + sc8, &vt[nb][r0 * 64]);
      gld_lds16(Vt + (size_t)(r0 + 8 + srow) * T_ + jn + sc8, &vt[nb][(r0 + 8) * 64]);
    }

    if (jb < qw + 32) {
      const char* kbase = (const char*)kt[cur];
      const char* vbase = (const char*)vt[cur];
      f32x4 s[2][4];
      // QK^T
#pragma unroll
      for (int jt = 0; jt < 4; jt++) {
        int krow = jt * 16 + l16;
        int kswz = (krow & 7) << 4;
        bf16x8 kf0 = *(const bf16x8*)(kbase + krow * 128 + ((lhi * 16) ^ kswz));
        bf16x8 kf1 = *(const bf16x8*)(kbase + krow * 128 + ((64 + lhi * 16) ^ kswz));
#pragma unroll
        for (int i = 0; i < 2; i++) {
          f32x4 z = (f32x4){0.f, 0.f, 0.f, 0.f};
          z = MFMA16(qf[i][0], kf0, z);
          s[i][jt] = MFMA16(qf[i][1], kf1, z);
        }
      }
      // causal mask (only near diagonal)
      if (jb + 63 > qw) {
#pragma unroll
        for (int i = 0; i < 2; i++)
#pragma unroll
          for (int jt = 0; jt < 4; jt++)
#pragma unroll
            for (int rr = 0; rr < 4; rr++)
              if (jb + jt * 16 + l16 > qw + i * 16 + 4 * lhi + rr) s[i][jt][rr] = -1e30f;
      }
      // online softmax (rows spread over 16-lane groups)
      float mx[2][4];
#pragma unroll
      for (int i = 0; i < 2; i++)
#pragma unroll
        for (int rr = 0; rr < 4; rr++)
          mx[i][rr] = fmaxf(fmaxf(s[0 + i * 0][0][0] * 0.f + s[i][0][rr], s[i][1][rr]),
                            fmaxf(s[i][2][rr], s[i][3][rr]));
#pragma unroll
      for (int off = 1; off < 16; off <<= 1)
#pragma unroll
        for (int i = 0; i < 2; i++)
#pragma unroll
          for (int rr = 0; rr < 4; rr++) mx[i][rr] = fmaxf(mx[i][rr], __shfl_xor(mx[i][rr], off));
      float sum[2][4], sc[2][4];
#pragma unroll
      for (int i = 0; i < 2; i++)
#pragma unroll
        for (int rr = 0; rr < 4; rr++) {
          float mn = fmaxf(m_r[i][rr], mx[i][rr]);
          sc[i][rr] = __expf(m_r[i][rr] - mn);
          m_r[i][rr] = mn;
          float su = 0.f;
#pragma unroll
          for (int jt = 0; jt < 4; jt++) {
            s[i][jt][rr] = __expf(s[i][jt][rr] - mn);
            su += s[i][jt][rr];
          }
          sum[i][rr] = su;
        }
#pragma unroll
      for (int off = 1; off < 16; off <<= 1)
#pragma unroll
        for (int i = 0; i < 2; i++)
#pragma unroll
          for (int rr = 0; rr < 4; rr++) sum[i][rr] += __shfl_xor(sum[i][rr], off);
#pragma unroll
      for (int i = 0; i < 2; i++)
#pragma unroll
        for (int rr = 0; rr < 4; rr++) l_r[i][rr] = l_r[i][rr] * sc[i][rr] + sum[i][rr];
#pragma unroll
      for (int i = 0; i < 2; i++)
#pragma unroll
        for (int dt = 0; dt < 4; dt++)
#pragma unroll
          for (int rr = 0; rr < 4; rr++) acc[i][dt][rr] *= sc[i][rr];

      // stage P into per-wave swizzled LDS
#pragma unroll
      for (int i = 0; i < 2; i++)
#pragma unroll
        for (int jt = 0; jt < 4; jt++)
#pragma unroll
          for (int rr = 0; rr < 4; rr++) {
            int prow = i * 16 + 4 * lhi + rr;
            int byte = prow * 128 + ((jt * 32 + 2 * l16) ^ ((prow & 7) << 4));
            *(bf16*)((char*)pb + byte) = (bf16)s[i][jt][rr];
          }
      bf16x8 pf[2][2];
#pragma unroll
      for (int i = 0; i < 2; i++)
#pragma unroll
        for (int kk = 0; kk < 2; kk++) {
          int prow = i * 16 + l16;
          int byte = prow * 128 + (((kk * 64) + lhi * 16) ^ ((prow & 7) << 4));
          pf[i][kk] = *(const bf16x8*)((const char*)pb + byte);
        }
      // PV
#pragma unroll
      for (int dt = 0; dt < 4; dt++) {
        int vrow = dt * 16 + l16;
        int vswz = (vrow & 7) << 4;
        bf16x8 vf0 = *(const bf16x8*)(vbase + vrow * 128 + ((lhi * 16) ^ vswz));
        bf16x8 vf1 = *(const bf16x8*)(vbase + vrow * 128 + ((64 + lhi * 16) ^ vswz));
#pragma unroll
        for (int i = 0; i < 2; i++) {
          acc[i][dt] = MFMA16(pf[i][0], vf0, acc[i][dt]);
          acc[i][dt] = MFMA16(pf[i][1], vf1, acc[i][dt]);
        }
      }
    }
    __syncthreads();
  }

  int b = bh >> 4, h = bh & 15;
#pragma unroll
  for (int i = 0; i < 2; i++)
#pragma unroll
    for (int dt = 0; dt < 4; dt++)
#pragma unroll
      for (int rr = 0; rr < 4; rr++) {
        int row = qw + i * 16 + 4 * lhi + rr;
        obuf[((size_t)(b * T_ + row)) * D_ + h * 64 + dt * 16 + l16] =
            (bf16)(acc[i][dt][rr] / l_r[i][rr]);
      }
}

extern "C" void kernel_launch(void* const* d_in, const int* in_sizes, int n_in, void* d_out,
                              int out_size, void* d_ws, size_t ws_size, hipStream_t stream) {
  const float* x = (const float*)d_in[0];
  const float* wqkv = (const float*)d_in[1];
  const float* wo = (const float*)d_in[2];
  float* out = (float*)d_out;
  char* ws = (char*)d_ws;

  bf16* xb = (bf16*)ws;                     // 16 MB  [8192][1024]
  bf16* wqkvt = (bf16*)(ws + (16u << 20));  // 6 MB   [3072][1024]
  bf16* wot = (bf16*)(ws + (22u << 20));    // 2 MB   [1024][1024]
  bf16* qb = (bf16*)(ws + (24u << 20));     // 16 MB  [B,H,T,64]
  bf16* kb = (bf16*)(ws + (40u << 20));     // 16 MB  [B,H,T,64]
  bf16* vb = (bf16*)(ws + (56u << 20));     // 16 MB  [B,H,T,64]
  bf16* vtb = (bf16*)(ws + (72u << 20));    // 16 MB  [B,H,64,T]
  bf16* ao = (bf16*)(ws + (88u << 20));     // 16 MB  [8192][1024]

  cvt_f32_bf16<<<8192, 256, 0, stream>>>(x, xb);
  transpose_f32_bf16<<<dim3(96, 32), dim3(32, 8), 0, stream>>>(wqkv, wqkvt, 1024, 3072);
  transpose_f32_bf16<<<dim3(32, 32), dim3(32, 8), 0, stream>>>(wo, wot, 1024, 1024);
  gemm_bt<0><<<dim3(24, 64), 256, 0, stream>>>(xb, wqkvt, qb, kb, vb, nullptr,
                                               B_ * T_, 3 * D_, D_);
  transpose_v<<<dim3(64, 64), dim3(32, 8), 0, stream>>>(vb, vtb);
  attn_kernel<<<1024, 256, 0, stream>>>(qb, kb, vtb, ao);
  gemm_bt<1><<<dim3(8, 64), 256, 0, stream>>>(ao, wot, nullptr, nullptr, nullptr, out,
                                              B_ * T_, D_, D_);
}